// Round 3
// baseline (369.358 us; speedup 1.0000x reference)
//
#include <hip/hip_runtime.h>

#define IMG_H 512
#define IMG_W 512
#define IMGSZ (IMG_H * IMG_W)
#define NIMG 48          // B*C = 16*3
#define NB 16
#define NPOS 4096
#define NPIX (12582912)  // 48 * 512 * 512

// SSIM tile config
#define TH 16
#define TW 64
#define HR (TH + 10)     // 26
#define HC (TW + 10)     // 74

__global__ __launch_bounds__(256) void ssim_perc_kernel(
    const float* __restrict__ pred, const float* __restrict__ targ,
    double* __restrict__ acc /* [0]=ssim_sum, [1]=perc_sum */)
{
    __shared__ float sx[HR][HC + 2];
    __shared__ float sy[HR][HC + 2];
    __shared__ float hs[5][HR][TW];
    __shared__ float red[2][4];

    const int bid = blockIdx.x;
    const int img = bid >> 8;        // 256 tiles per image
    const int rem = bid & 255;
    const int trow = rem >> 3;       // 32 tile-rows
    const int tcol = rem & 7;        // 8 tile-cols
    const int row0 = trow * TH;
    const int col0 = tcol * TW;
    const float* __restrict__ pimg = pred + (size_t)img * IMGSZ;
    const float* __restrict__ timg = targ + (size_t)img * IMGSZ;
    const int tid = threadIdx.x;

    // ---- load halo (zero padded at image borders) ----
    for (int i = tid; i < HR * HC; i += 256) {
        int r = i / HC, c = i % HC;
        int gr = row0 + r - 5, gc = col0 + c - 5;
        float xv = 0.f, yv = 0.f;
        if (gr >= 0 && gr < IMG_H && gc >= 0 && gc < IMG_W) {
            int gi = gr * IMG_W + gc;
            xv = pimg[gi];
            yv = timg[gi];
        }
        sx[r][c] = xv;
        sy[r][c] = yv;
    }
    __syncthreads();

    // ---- horizontal box sums (width 11) for x, y, x^2, y^2, xy ----
    for (int i = tid; i < HR * TW; i += 256) {
        int r = i >> 6, c = i & 63;   // TW == 64
        float hx = 0.f, hy = 0.f, hx2 = 0.f, hy2 = 0.f, hxy = 0.f;
#pragma unroll
        for (int dx = 0; dx < 11; ++dx) {
            float xv = sx[r][c + dx];
            float yv = sy[r][c + dx];
            hx += xv;
            hy += yv;
            hx2 = fmaf(xv, xv, hx2);
            hy2 = fmaf(yv, yv, hy2);
            hxy = fmaf(xv, yv, hxy);
        }
        hs[0][r][c] = hx;
        hs[1][r][c] = hy;
        hs[2][r][c] = hx2;
        hs[3][r][c] = hy2;
        hs[4][r][c] = hxy;
    }
    __syncthreads();

    // ---- vertical box sums (height 11) + SSIM + perceptual ----
    float ssim_acc = 0.f, perc_acc = 0.f;
    const float inv121 = 1.0f / 121.0f;
    const float C1c = 1e-4f;   // 0.01^2
    const float C2c = 9e-4f;   // 0.03^2
    for (int i = tid; i < TH * TW; i += 256) {
        int r = i >> 6, c = i & 63;
        float Sx = 0.f, Sy = 0.f, Sx2 = 0.f, Sy2 = 0.f, Sxy = 0.f;
#pragma unroll
        for (int dy = 0; dy < 11; ++dy) {
            Sx  += hs[0][r + dy][c];
            Sy  += hs[1][r + dy][c];
            Sx2 += hs[2][r + dy][c];
            Sy2 += hs[3][r + dy][c];
            Sxy += hs[4][r + dy][c];
        }
        float mux = Sx * inv121;
        float muy = Sy * inv121;
        float sgx = Sx2 * inv121 - mux * mux;
        float sgy = Sy2 * inv121 - muy * muy;
        float sgxy = Sxy * inv121 - mux * muy;
        float num = (2.f * mux * muy + C1c) * (2.f * sgxy + C2c);
        float den = (mux * mux + muy * muy + C1c) * (sgx + sgy + C2c);
        ssim_acc += num / den;
        float xv = sx[r + 5][c + 5];
        float yv = sy[r + 5][c + 5];
        perc_acc += fabsf(xv - yv);
    }

    // ---- block reduction ----
#pragma unroll
    for (int off = 32; off > 0; off >>= 1) {
        ssim_acc += __shfl_down(ssim_acc, off);
        perc_acc += __shfl_down(perc_acc, off);
    }
    int wave = tid >> 6, lane = tid & 63;
    if (lane == 0) { red[0][wave] = ssim_acc; red[1][wave] = perc_acc; }
    __syncthreads();
    if (tid == 0) {
        float s = red[0][0] + red[0][1] + red[0][2] + red[0][3];
        float p = red[1][0] + red[1][1] + red[1][2] + red[1][3];
        atomicAdd(&acc[0], (double)s);
        atomicAdd(&acc[1], (double)p);
    }
}

__global__ __launch_bounds__(256) void sampled_kernel(
    const float* __restrict__ pred, const float* __restrict__ targ,
    const int* __restrict__ pos32, const float* __restrict__ imp,
    double* __restrict__ acc /* [2]=sampled_sum */)
{
    __shared__ int mode64;       // 1 if positions stored as int64
    __shared__ float red[4];
    const int tid = threadIdx.x;
    const int n = blockIdx.x * 256 + tid;

    if (tid == 0) mode64 = 1;
    __syncthreads();
    // int64 layout: every odd 32-bit word is a high word == 0 (values < 512).
    // int32 layout: odd words are v coords — ~never all zero in a block.
    if (n < NPOS) {
        if (pos32[2 * n + 1] != 0) mode64 = 0;
    }
    __syncthreads();

    float val = 0.f;
    if (n < NPOS) {
        int u, v;
        if (mode64) { u = pos32[4 * n]; v = pos32[4 * n + 2]; }
        else        { u = pos32[2 * n]; v = pos32[2 * n + 1]; }
        int off = u * IMG_W + v;
        float se = 0.f;
#pragma unroll 4
        for (int j = 0; j < NIMG; ++j) {
            float d = pred[j * IMGSZ + off] - targ[j * IMGSZ + off];
            se = fmaf(d, d, se);
        }
        float wsum = 0.f;
#pragma unroll 4
        for (int b = 0; b < NB; ++b)
            wsum += 1.0f / (imp[b * IMGSZ + off] + 0.1f);
        val = (wsum * (1.0f / 16.0f)) * (se * (1.0f / 48.0f));
    }

#pragma unroll
    for (int off2 = 32; off2 > 0; off2 >>= 1)
        val += __shfl_down(val, off2);
    int wave = tid >> 6, lane = tid & 63;
    if (lane == 0) red[wave] = val;
    __syncthreads();
    if (tid == 0) {
        float s = red[0] + red[1] + red[2] + red[3];
        atomicAdd(&acc[2], (double)s);
    }
}

__global__ void finalize_kernel(const double* __restrict__ acc,
                                float* __restrict__ out)
{
    if (threadIdx.x == 0 && blockIdx.x == 0) {
        double sampled = acc[2] / (double)NPOS;
        double perc = acc[1] / (double)NPIX;
        double structural = 1.0 - acc[0] / (double)NPIX;
        double total = 0.3 * sampled + 0.4 * perc + 0.2 * structural;
        out[0] = (float)total;
        out[1] = (float)sampled;
        out[2] = (float)perc;
        out[3] = (float)structural;
        out[4] = 0.0f;
    }
}

extern "C" void kernel_launch(void* const* d_in, const int* in_sizes, int n_in,
                              void* d_out, int out_size, void* d_ws, size_t ws_size,
                              hipStream_t stream)
{
    const float* pred = (const float*)d_in[0];
    const float* targ = (const float*)d_in[1];
    const int* pos = (const int*)d_in[2];
    const float* imp = (const float*)d_in[3];
    float* out = (float*)d_out;
    double* acc = (double*)d_ws;

    hipMemsetAsync(acc, 0, 3 * sizeof(double), stream);

    hipLaunchKernelGGL(sampled_kernel, dim3(NPOS / 256), dim3(256), 0, stream,
                       pred, targ, pos, imp, acc);

    // 48 images * (512/16) * (512/64) = 48 * 256 = 12288 tiles
    hipLaunchKernelGGL(ssim_perc_kernel, dim3(12288), dim3(256), 0, stream,
                       pred, targ, acc);

    hipLaunchKernelGGL(finalize_kernel, dim3(1), dim3(64), 0, stream, acc, out);
}

// Round 4
// 122.918 us; speedup vs baseline: 3.0049x; 3.0049x over previous
//
#include <hip/hip_runtime.h>

#define IMG_H 512
#define IMG_W 512
#define IMGSZ (IMG_H * IMG_W)
#define NIMG 48          // B*C = 16*3
#define NB 16
#define NPOS 4096
#define NPIX (12582912)  // 48 * 512 * 512

// Band-streaming SSIM config
#define BH 16                     // output rows per band
#define NBANDS (IMG_H / BH)       // 32
#define GRID_SSIM (NIMG * NBANDS) // 1536 blocks = 6 per CU
#define VROW_L 524                // logical cols: -6..517 (offset +6)
#define VROW_P 544                // physical (pad-every-32 swizzle), 523+16=539 max

// pad-every-32 swizzle: stride-2 column access becomes 2-way (free) not 4-way
__device__ __forceinline__ int phys(int i) { return i + (i >> 5); }

__device__ __forceinline__ float ssim_val(float Sx, float Sy, float Sxx,
                                          float Syy, float Sxy)
{
    const float inv121 = 1.0f / 121.0f;
    const float C1c = 1e-4f;
    const float C2c = 9e-4f;
    float mux = Sx * inv121;
    float muy = Sy * inv121;
    float sgx = Sxx * inv121 - mux * mux;
    float sgy = Syy * inv121 - muy * muy;
    float sgxy = Sxy * inv121 - mux * muy;
    float num = (2.f * mux * muy + C1c) * (2.f * sgxy + C2c);
    float den = (mux * mux + muy * muy + C1c) * (sgx + sgy + C2c);
    return num / den;
}

__global__ __launch_bounds__(256, 6) void ssim_perc_kernel(
    const float* __restrict__ pred, const float* __restrict__ targ,
    double* __restrict__ acc /* [0]=ssim_sum, [1]=perc_sum */)
{
    __shared__ float vrow[5][VROW_P];
    __shared__ float redbuf[2][4];

    const int bid = blockIdx.x;
    const int img = bid >> 5;        // NBANDS == 32 bands per image
    const int band = bid & 31;
    const int row0 = band * BH;
    const float* __restrict__ pimg = pred + (size_t)img * IMGSZ;
    const float* __restrict__ timg = targ + (size_t)img * IMGSZ;
    const int t = threadIdx.x;
    const int c0 = 2 * t;            // this thread owns columns c0, c0+1

    // zero LDS once (pad columns stay zero forever)
    float* vflat = &vrow[0][0];
    for (int i = t; i < 5 * VROW_P; i += 256) vflat[i] = 0.f;
    __syncthreads();

    // vertical running window sums (11 rows) for cols c0 (v*) and c0+1 (w*)
    float vx = 0.f, vy = 0.f, vxx = 0.f, vyy = 0.f, vxy = 0.f;
    float wx = 0.f, wy = 0.f, wxx = 0.f, wyy = 0.f, wxy = 0.f;
    float perc = 0.f, ssim_s = 0.f;

    // ---- warm-up: rows row0-5 .. row0+5 ----
    for (int k = 0; k < 11; ++k) {
        int gr = row0 - 5 + k;
        float2 xv = make_float2(0.f, 0.f), yv = make_float2(0.f, 0.f);
        if (gr >= 0 && gr < IMG_H) {
            xv = *(const float2*)(pimg + gr * IMG_W + c0);
            yv = *(const float2*)(timg + gr * IMG_W + c0);
            if (gr >= row0)   // in-band part of warm-up (gr <= row0+5 < row0+BH)
                perc += fabsf(xv.x - yv.x) + fabsf(xv.y - yv.y);
        }
        vx += xv.x; vy += yv.x;
        vxx = fmaf(xv.x, xv.x, vxx);
        vyy = fmaf(yv.x, yv.x, vyy);
        vxy = fmaf(xv.x, yv.x, vxy);
        wx += xv.y; wy += yv.y;
        wxx = fmaf(xv.y, xv.y, wxx);
        wyy = fmaf(yv.y, yv.y, wyy);
        wxy = fmaf(xv.y, yv.y, wxy);
    }

    // ---- stream down the band ----
    for (int r = 0; r < BH; ++r) {
        if (r > 0) {
            int ge = row0 + r + 5;   // entering row (>= row0+6 > 0)
            int gl = row0 + r - 6;   // leaving row  (<= row0+BH-7 < IMG_H)
            float2 xe = make_float2(0.f, 0.f), ye = make_float2(0.f, 0.f);
            float2 xl = make_float2(0.f, 0.f), yl = make_float2(0.f, 0.f);
            if (ge < IMG_H) {
                xe = *(const float2*)(pimg + ge * IMG_W + c0);
                ye = *(const float2*)(timg + ge * IMG_W + c0);
                if (ge < row0 + BH)   // entering row inside this band
                    perc += fabsf(xe.x - ye.x) + fabsf(xe.y - ye.y);
            }
            if (gl >= 0) {
                xl = *(const float2*)(pimg + gl * IMG_W + c0);
                yl = *(const float2*)(timg + gl * IMG_W + c0);
            }
            vx += xe.x - xl.x;
            vy += ye.x - yl.x;
            vxx = fmaf(-xl.x, xl.x, fmaf(xe.x, xe.x, vxx));
            vyy = fmaf(-yl.x, yl.x, fmaf(ye.x, ye.x, vyy));
            vxy = fmaf(-xl.x, yl.x, fmaf(xe.x, ye.x, vxy));
            wx += xe.y - xl.y;
            wy += ye.y - yl.y;
            wxx = fmaf(-xl.y, xl.y, fmaf(xe.y, xe.y, wxx));
            wyy = fmaf(-yl.y, yl.y, fmaf(ye.y, ye.y, wyy));
            wxy = fmaf(-xl.y, yl.y, fmaf(xe.y, ye.y, wxy));
        }

        // publish vertical sums for this output row
        int p0 = phys(6 + c0), p1 = phys(6 + c0 + 1);
        vrow[0][p0] = vx;  vrow[0][p1] = wx;
        vrow[1][p0] = vy;  vrow[1][p1] = wy;
        vrow[2][p0] = vxx; vrow[2][p1] = wxx;
        vrow[3][p0] = vyy; vrow[3][p1] = wyy;
        vrow[4][p0] = vxy; vrow[4][p1] = wxy;
        __syncthreads();

        // horizontal 11-tap for col c0, then slide to c0+1
        float Sx = 0.f, Sy = 0.f, Sxx = 0.f, Syy = 0.f, Sxy = 0.f;
        int base = 6 + c0 - 5;
#pragma unroll
        for (int dx = 0; dx < 11; ++dx) {
            int pi = phys(base + dx);
            Sx  += vrow[0][pi];
            Sy  += vrow[1][pi];
            Sxx += vrow[2][pi];
            Syy += vrow[3][pi];
            Sxy += vrow[4][pi];
        }
        ssim_s += ssim_val(Sx, Sy, Sxx, Syy, Sxy);

        int pa = phys(6 + c0 + 6), ps = phys(6 + c0 - 5);
        Sx  += vrow[0][pa] - vrow[0][ps];
        Sy  += vrow[1][pa] - vrow[1][ps];
        Sxx += vrow[2][pa] - vrow[2][ps];
        Syy += vrow[3][pa] - vrow[3][ps];
        Sxy += vrow[4][pa] - vrow[4][ps];
        ssim_s += ssim_val(Sx, Sy, Sxx, Syy, Sxy);

        __syncthreads();   // WAR: next row overwrites vrow
    }

    // ---- block reduction ----
#pragma unroll
    for (int off = 32; off > 0; off >>= 1) {
        ssim_s += __shfl_down(ssim_s, off);
        perc   += __shfl_down(perc, off);
    }
    int wave = t >> 6, lane = t & 63;
    if (lane == 0) { redbuf[0][wave] = ssim_s; redbuf[1][wave] = perc; }
    __syncthreads();
    if (t == 0) {
        float s = redbuf[0][0] + redbuf[0][1] + redbuf[0][2] + redbuf[0][3];
        float p = redbuf[1][0] + redbuf[1][1] + redbuf[1][2] + redbuf[1][3];
        atomicAdd(&acc[0], (double)s);
        atomicAdd(&acc[1], (double)p);
    }
}

__global__ __launch_bounds__(256) void sampled_kernel(
    const float* __restrict__ pred, const float* __restrict__ targ,
    const int* __restrict__ pos32, const float* __restrict__ imp,
    double* __restrict__ acc /* [2]=sampled_sum */)
{
    __shared__ int mode64;       // 1 if positions stored as int64
    __shared__ float red[4];
    const int tid = threadIdx.x;
    const int n = blockIdx.x * 256 + tid;

    if (tid == 0) mode64 = 1;
    __syncthreads();
    if (n < NPOS) {
        if (pos32[2 * n + 1] != 0) mode64 = 0;
    }
    __syncthreads();

    float val = 0.f;
    if (n < NPOS) {
        int u, v;
        if (mode64) { u = pos32[4 * n]; v = pos32[4 * n + 2]; }
        else        { u = pos32[2 * n]; v = pos32[2 * n + 1]; }
        int off = u * IMG_W + v;
        float se = 0.f;
#pragma unroll 4
        for (int j = 0; j < NIMG; ++j) {
            float d = pred[j * IMGSZ + off] - targ[j * IMGSZ + off];
            se = fmaf(d, d, se);
        }
        float wsum = 0.f;
#pragma unroll 4
        for (int b = 0; b < NB; ++b)
            wsum += 1.0f / (imp[b * IMGSZ + off] + 0.1f);
        val = (wsum * (1.0f / 16.0f)) * (se * (1.0f / 48.0f));
    }

#pragma unroll
    for (int off2 = 32; off2 > 0; off2 >>= 1)
        val += __shfl_down(val, off2);
    int wave = tid >> 6, lane = tid & 63;
    if (lane == 0) red[wave] = val;
    __syncthreads();
    if (tid == 0) {
        float s = red[0] + red[1] + red[2] + red[3];
        atomicAdd(&acc[2], (double)s);
    }
}

__global__ void finalize_kernel(const double* __restrict__ acc,
                                float* __restrict__ out)
{
    if (threadIdx.x == 0 && blockIdx.x == 0) {
        double sampled = acc[2] / (double)NPOS;
        double perc = acc[1] / (double)NPIX;
        double structural = 1.0 - acc[0] / (double)NPIX;
        double total = 0.3 * sampled + 0.4 * perc + 0.2 * structural;
        out[0] = (float)total;
        out[1] = (float)sampled;
        out[2] = (float)perc;
        out[3] = (float)structural;
        out[4] = 0.0f;
    }
}

extern "C" void kernel_launch(void* const* d_in, const int* in_sizes, int n_in,
                              void* d_out, int out_size, void* d_ws, size_t ws_size,
                              hipStream_t stream)
{
    const float* pred = (const float*)d_in[0];
    const float* targ = (const float*)d_in[1];
    const int* pos = (const int*)d_in[2];
    const float* imp = (const float*)d_in[3];
    float* out = (float*)d_out;
    double* acc = (double*)d_ws;

    hipMemsetAsync(acc, 0, 3 * sizeof(double), stream);

    hipLaunchKernelGGL(sampled_kernel, dim3(NPOS / 256), dim3(256), 0, stream,
                       pred, targ, pos, imp, acc);

    hipLaunchKernelGGL(ssim_perc_kernel, dim3(GRID_SSIM), dim3(256), 0, stream,
                       pred, targ, acc);

    hipLaunchKernelGGL(finalize_kernel, dim3(1), dim3(64), 0, stream, acc, out);
}